// Round 8
// baseline (225.292 us; speedup 1.0000x reference)
//
#include <hip/hip_runtime.h>
#include <math.h>

#define LATN 721
#define LONN 1440
#define NLEV 13
#define NBATCH 2
#define SLICE (LATN * LONN)              // 1,038,240
#define BATSTRIDE (NLEV * SLICE)

// row-streaming geometry: lane owns 2 cols (float2); wave = 128 cols, 124 outputs
#define OUTW 124                         // outputs per wave
#define WGOUT 496                        // outputs per WG (4 waves)
#define SEGS 3                           // ceil(1440/496)
#define NWGX (LATN * SEGS)               // 2163

// ---- ws float layout ----
#define NBANK      128
#define BANKSTRIDE 64
#define WS_ACC     0                     // [NBANK*BANKSTRIDE]
#define ACC_SUM    0        // [26] per (b,l) sums
#define ACC_SSQ    26       // [2]  per-batch total sum-of-squares
#define ACC_GRAD   28
#define ACC_MASS   29
#define N_ACC      30
#define WS_INVDX   (NBANK * BANKSTRIDE)          // [721]
#define WS_FCOR    (WS_INVDX + LATN)             // [721]
#define WS_W       (WS_FCOR + LATN)              // [13]
#define WS_INVDP   (WS_W + NLEV)
#define WS_INV2DP  (WS_INVDP + 1)

constexpr float INV_R     = (float)(1.0 / 6371000.0);
constexpr float INV_DLAT  = (float)(720.0 / M_PI);
constexpr float INV_2DLAT = (float)(360.0 / M_PI);
constexpr float INV_DLON  = (float)(1440.0 / (2.0 * M_PI));
constexpr float INV_2DLON = (float)(720.0 / (2.0 * M_PI));
constexpr float QG_COEF   = 1e-4f;   // F0^2 / N^2

// ---------------- setup: row tables, weights, zero accumulators ----------------
__global__ void pl_setup_kernel(const float* __restrict__ plev, float* __restrict__ ws) {
    const int t = threadIdx.x;
    if (t < LATN) {
        double lat;
        if (t == 0)            lat = (double)(-(float)(M_PI / 2.0));
        else if (t == LATN-1)  lat = (double)( (float)(M_PI / 2.0));
        else                   lat = (double)((float)(-M_PI / 2.0 + (double)t * (M_PI / 720.0)));
        double c = cos(lat);
        if (c < 1e-8) c = 1e-8;                      // matches jnp.clip(cos, 1e-8)
        ws[WS_INVDX + t] = (float)(1.0 / (6371000.0 * c));
        ws[WS_FCOR  + t] = (float)(2.0 * 7.292e-05 * sin(lat));
    }
    if (t < NLEV) {
        float p[NLEV];
        #pragma unroll
        for (int l = 0; l < NLEV; ++l) p[l] = plev[l] * 100.0f;
        float dpl[NLEV-1];
        #pragma unroll
        for (int l = 0; l < NLEV-1; ++l) dpl[l] = p[l+1] - p[l];
        float raw;
        if (t == 0)            raw = dpl[0] * 0.5f;
        else if (t == NLEV-1)  raw = dpl[NLEV-2] * 0.5f;
        else                   raw = (dpl[t-1] + dpl[t]) * 0.5f;
        float s = dpl[0] * 0.5f + dpl[NLEV-2] * 0.5f;
        #pragma unroll
        for (int l = 1; l < NLEV-1; ++l) s += (dpl[l-1] + dpl[l]) * 0.5f;
        if (s < 1e-8f) s = 1e-8f;
        ws[WS_W + t] = raw / s;
    }
    if (t == 0) {
        float sd = 0.f;
        for (int l = 0; l < NLEV-1; ++l) sd += plev[l+1] - plev[l];
        float dp = sd / (float)(NLEV-1) * 100.0f;    // mean(diff)*100 (hPa->Pa)
        ws[WS_INVDP]  = 1.0f / dp;
        ws[WS_INV2DP] = 1.0f / (2.0f * dp);
    }
    for (int z = t; z < NBANK * BANKSTRIDE; z += 1024) ws[WS_ACC + z] = 0.0f;
}

// ---------------- helpers ----------------
__device__ __forceinline__ int swz_nwg(int orig, int nwg) {
    // bijective XCD-chunk swizzle (m204)
    const int q = nwg >> 3, r = nwg & 7;
    const int x = orig & 7, k = orig >> 3;
    return (x < r ? x * (q + 1) : r * (q + 1) + (x - r) * q) + k;
}

__device__ __forceinline__ float2 ld2(const float* p) {
    return *reinterpret_cast<const float2*>(p);
}
__device__ __forceinline__ float2 sm2(float2 a, float2 b, float s) {   // (a-b)*s
    return make_float2((a.x - b.x) * s, (a.y - b.y) * s);
}

// ---------------- row-streaming fused kernel, 2 cols/lane (float2 loads) ----------------
// thread = 2 (row,col) points, all levels; 3-row qg recompute; fused vertical pipeline
__launch_bounds__(256, 4)
__global__ void pl_row2_kernel(const float* __restrict__ u, const float* __restrict__ v,
                               float* __restrict__ ws)
{
    __shared__ float red[16][17];

    const int tid  = threadIdx.x;
    const int lane = tid & 63, w = tid >> 6;
    const int b  = blockIdx.y;
    const int wg = swz_nwg(blockIdx.x, NWGX);
    const int r   = wg / SEGS, seg = wg - r * SEGS;

    const int out0  = seg * WGOUT + w * OUTW;
    const int c0_un = out0 - 2 + 2 * lane;          // col of .x (lane 0/63 pure halo)
    const int cb = max(0, min(c0_un, LONN - 2));    // even -> 8B-aligned pair base
    const float m0 = (lane >= 1 && lane <= 62 && c0_un     < LONN) ? 1.f : 0.f;
    const float m1 = (lane >= 1 && lane <= 62 && c0_un + 1 < LONN) ? 1.f : 0.f;
    const bool e0L = (c0_un == 0);                  // .x is col 0 (one-sided, in-lane)
    const bool e1R = (c0_un + 1 == LONN - 1);       // .y is col 1439 (one-sided, in-lane)

    const int rm1 = max(r - 1, 0), rp1 = min(r + 1, LATN - 1);
    const int rm2 = max(r - 2, 0), rp2 = min(r + 2, LATN - 1);
    const bool rTop = (r == 0), rBot = (r == LATN - 1);

    const float* ub = u + (size_t)b * BATSTRIDE;
    const float* vb = v + (size_t)b * BATSTRIDE;

    const float idp = ws[WS_INVDP], i2dp = ws[WS_INV2DP];
    const float ixm = ws[WS_INVDX + rm1], ixc = ws[WS_INVDX + r], ixp = ws[WS_INVDX + rp1];
    const float fc_m = ws[WS_FCOR + rm1], fc_c = ws[WS_FCOR + r], fc_p = ws[WS_FCOR + rp1];

    const float eC0 = e0L ? INV_DLON : INV_2DLON;
    const float eC1 = e1R ? INV_DLON : INV_2DLON;
    const float scm0 = eC0 * ixm, scm1 = eC1 * ixm;
    const float scc0 = eC0 * ixc, scc1 = eC1 * ixc;
    const float scp0 = eC0 * ixp, scp1 = eC1 * ixp;
    const float sr_c = ((r   == 0 || r == LATN - 1) ? INV_DLAT : INV_2DLAT) * INV_R;
    const float sr_m = ((rm1 == 0)                  ? INV_DLAT : INV_2DLAT) * INV_R;
    const float sr_p = ((rp1 == LATN - 1)           ? INV_DLAT : INV_2DLAT) * INV_R;
    const float siR = sr_c, sjx0 = scc0, sjx1 = scc1;

    // 5 shared element offsets (u uses all 5; v reuses rm1/r/rp1)
    const int o_um2 = rm2 * LONN + cb, o_um1 = rm1 * LONN + cb, o_u0 = r * LONN + cb;
    const int o_up1 = rp1 * LONN + cb, o_up2 = rp2 * LONN + cb;

    float vals[16];
    #pragma unroll
    for (int k = 0; k < 16; ++k) vals[k] = 0.f;
    float ssqt = 0.f, grad = 0.f;
    float2 wu  = make_float2(0.f, 0.f);
    float2 wvm = make_float2(0.f, 0.f);
    float2 wvp = make_float2(0.f, 0.f);

    // qg emission (k is compile-time constant at every call site)
    auto qgf = [&](float2 vo, float fc, float2 vpp) -> float2 {
        return make_float2(vo.x + fc + QG_COEF * vpp.x, vo.y + fc + QG_COEF * vpp.y);
    };
    auto consume = [&](int k, float2 qm, float2 qc, float2 qp) {
        const float qx = qc.x * m0, qy = qc.y * m1;
        vals[k] += qx + qy;
        ssqt += qx * qx + qy * qy;
        const float glx = (qp.x - qm.x) * siR, gly = (qp.y - qm.y) * siR;
        const float qLs = __shfl_up(qc.y, 1), qRs = __shfl_down(qc.x, 1);
        const float qLx = e0L ? qc.x : qLs;
        const float qRy = e1R ? qc.y : qRs;
        const float gnx = (qc.y - qLx) * sjx0;
        const float gny = (qRy  - qc.x) * sjx1;
        grad += m0 * (glx * glx + gnx * gnx) + m1 * (gly * gly + gny * gny);
    };

    // vort history (liveness-windowed: emission at l uses only vo[l-2], so the
    // compiler keeps ~3 levels live) + rolling vp1 state per row-stream
    float2 vom[NLEV], voc[NLEV], vop[NLEV];
    float2 pma, pmb, pca, pcb, ppa, ppb;

    const float* pu = ub;
    const float* pv = vb;
    #pragma unroll
    for (int l = 0; l < NLEV; ++l) {
        const float wl = ws[WS_W + l];               // uniform -> SGPR
        const float2 um2 = ld2(pu + o_um2), um1 = ld2(pu + o_um1), u00 = ld2(pu + o_u0);
        const float2 up1 = ld2(pu + o_up1), up2v = ld2(pu + o_up2);
        const float2 vm1 = ld2(pv + o_um1), v00 = ld2(pv + o_u0), vpl = ld2(pv + o_up1);

        // col neighbors: shfl (all lanes participate), then edge in-lane select
        const float vm1L = __shfl_up(vm1.y, 1), vm1R = __shfl_down(vm1.x, 1);
        const float v00L = __shfl_up(v00.y, 1), v00R = __shfl_down(v00.x, 1);
        const float vplL = __shfl_up(vpl.y, 1), vplR = __shfl_down(vpl.x, 1);
        const float vmlx = e0L ? vm1.x : vm1L;
        const float vmry = e1R ? vm1.y : vm1R;
        const float v0lx = e0L ? v00.x : v00L;
        const float v0ry = e1R ? v00.y : v00R;
        const float vplx = e0L ? vpl.x : vplL;
        const float vpry = e1R ? vpl.y : vplR;

        float2 vc, vmr, vpr;
        vc.x  = (v00.y - v0lx) * scc0 - (up1.x  - um1.x) * sr_c;
        vc.y  = (v0ry  - v00.x) * scc1 - (up1.y  - um1.y) * sr_c;
        vmr.x = (vm1.y - vmlx) * scm0 - (u00.x  - um2.x) * sr_m;
        vmr.y = (vmry  - vm1.x) * scm1 - (u00.y  - um2.y) * sr_m;
        vpr.x = (vpl.y - vplx) * scp0 - (up2v.x - u00.x) * sr_p;
        vpr.y = (vpry  - vpl.x) * scp1 - (up2v.y - u00.y) * sr_p;
        voc[l] = vc;
        vom[l] = rTop ? vc : vmr;                    // clamped halo row == own row
        vop[l] = rBot ? vc : vpr;

        wu.x  = fmaf(wl, u00.x, wu.x);   wu.y  = fmaf(wl, u00.y, wu.y);
        wvm.x = fmaf(wl, vm1.x, wvm.x);  wvm.y = fmaf(wl, vm1.y, wvm.y);
        wvp.x = fmaf(wl, vpl.x, wvp.x);  wvp.y = fmaf(wl, vpl.y, wvp.y);

        // fused vertical pipeline: vp1[l-1] ready -> emit qg[l-2]
        if (l == 1) {
            pmb = sm2(vom[1], vom[0], idp);          // vp1[0]
            pcb = sm2(voc[1], voc[0], idp);
            ppb = sm2(vop[1], vop[0], idp);
        } else if (l >= 2) {
            const float2 pmn = sm2(vom[l], vom[l-2], i2dp);   // vp1[l-1]
            const float2 pcn = sm2(voc[l], voc[l-2], i2dp);
            const float2 ppn = sm2(vop[l], vop[l-2], i2dp);
            if (l == 2) {
                consume(0, qgf(vom[0], fc_m, sm2(pmn, pmb, idp)),
                           qgf(voc[0], fc_c, sm2(pcn, pcb, idp)),
                           qgf(vop[0], fc_p, sm2(ppn, ppb, idp)));
            } else {
                consume(l - 2, qgf(vom[l-2], fc_m, sm2(pmn, pma, i2dp)),
                               qgf(voc[l-2], fc_c, sm2(pcn, pca, i2dp)),
                               qgf(vop[l-2], fc_p, sm2(ppn, ppa, i2dp)));
            }
            pma = pmb; pmb = pmn;
            pca = pcb; pcb = pcn;
            ppa = ppb; ppb = ppn;
        }
        pu += SLICE; pv += SLICE;                    // uniform SALU bump
    }
    // tail: vp1[12] one-sided; emit qg[11], qg[12]
    {
        const float2 pm12 = sm2(vom[NLEV-1], vom[NLEV-2], idp);
        const float2 pc12 = sm2(voc[NLEV-1], voc[NLEV-2], idp);
        const float2 pp12 = sm2(vop[NLEV-1], vop[NLEV-2], idp);
        consume(11, qgf(vom[11], fc_m, sm2(pm12, pma, i2dp)),
                    qgf(voc[11], fc_c, sm2(pc12, pca, i2dp)),
                    qgf(vop[11], fc_p, sm2(pp12, ppa, i2dp)));
        consume(12, qgf(vom[12], fc_m, sm2(pm12, pmb, idp)),
                    qgf(voc[12], fc_c, sm2(pc12, pcb, idp)),
                    qgf(vop[12], fc_p, sm2(pp12, ppb, idp)));
    }

    vals[13] += ssqt;
    vals[14] += grad;                                // terms masked at accumulation
    // mass: du/dx via wu neighbors (in-lane + shfl), dv/dy in-thread
    {
        const float uLs = __shfl_up(wu.y, 1), uRs = __shfl_down(wu.x, 1);
        const float uLx = e0L ? wu.x : uLs;
        const float uRy = e1R ? wu.y : uRs;
        const float cdx = (wu.y - uLx) * sjx0 + (wvp.x - wvm.x) * siR;
        const float cdy = (uRy  - wu.x) * sjx1 + (wvp.y - wvm.y) * siR;
        vals[15] += m0 * cdx * cdx + m1 * cdy * cdy;
    }

    // ---- reduction: 4-step 16-lane-group butterfly + LDS transpose (16 values) ----
    #pragma unroll
    for (int k = 0; k < 16; ++k) {
        float x = vals[k];
        x += __shfl_xor(x, 8, 64);
        x += __shfl_xor(x, 4, 64);
        x += __shfl_xor(x, 2, 64);
        x += __shfl_xor(x, 1, 64);
        vals[k] = x;
    }
    const int g = tid >> 4, k16 = tid & 15;
    float myv = vals[0];
    #pragma unroll
    for (int k = 1; k < 16; ++k) if (k16 == k) myv = vals[k];   // static-index select
    red[g][k16] = myv;
    __syncthreads();

    if (tid < 16) {
        const int k = tid;
        float s = 0.f;
        #pragma unroll
        for (int g2 = 0; g2 < 16; ++g2) s += red[g2][k];
        int target;
        if (k < 13)       target = ACC_SUM + b * 13 + k;
        else if (k == 13) target = ACC_SSQ + b;
        else if (k == 14) target = ACC_GRAD;
        else              target = ACC_MASS;
        const int bank = (b * NWGX + blockIdx.x) & (NBANK - 1);
        atomicAdd(&ws[WS_ACC + bank * BANKSTRIDE + target], s);
    }
}

// ---------------- finalize: sum banks, apply formulas ----------------
__global__ void pl_finalize_kernel(const float* __restrict__ ws, float* __restrict__ out) {
    __shared__ float tot[N_ACC];
    const int t = threadIdx.x;
    if (t < N_ACC) {
        float s = 0.f;
        for (int bk = 0; bk < NBANK; ++bk) s += ws[WS_ACC + bk * BANKSTRIDE + t];
        tot[t] = s;
    }
    __syncthreads();
    if (t == 0) {
        const float N = (float)SLICE;
        float s2 = 0.f;
        for (int s = 0; s < 2 * NLEV; ++s) s2 += tot[ACC_SUM + s] * tot[ACC_SUM + s];
        const float ssq = tot[ACC_SSQ + 0] + tot[ACC_SSQ + 1];
        float vmean = (ssq - s2 / N) / (N - 1.0f) * (1.0f / (2.0f * NLEV));
        float gmean = tot[ACC_GRAD] / (float)(NBATCH * NLEV * SLICE);
        float mmean = tot[ACC_MASS] / (float)(NBATCH * SLICE);
        out[0] = vmean + 0.1f * gmean + mmean;          // spectra_loss statically 0
    }
}

extern "C" void kernel_launch(void* const* d_in, const int* in_sizes, int n_in,
                              void* d_out, int out_size, void* d_ws, size_t ws_size,
                              hipStream_t stream) {
    const float* u    = (const float*)d_in[0];
    const float* v    = (const float*)d_in[1];
    const float* plev = (const float*)d_in[2];
    float* ws  = (float*)d_ws;
    float* out = (float*)d_out;

    hipLaunchKernelGGL(pl_setup_kernel, dim3(1), dim3(1024), 0, stream, plev, ws);
    hipLaunchKernelGGL(pl_row2_kernel, dim3(NWGX, NBATCH), dim3(256), 0, stream, u, v, ws);
    hipLaunchKernelGGL(pl_finalize_kernel, dim3(1), dim3(64), 0, stream, ws, out);
}

// Round 9
// 67.926 us; speedup vs baseline: 3.3167x; 3.3167x over previous
//
#include <hip/hip_runtime.h>
#include <math.h>

#define LATN 721
#define LONN 1440
#define NLEV 13
#define NBATCH 2
#define SLICE (LATN * LONN)              // 1,038,240
#define BATSTRIDE (NLEV * SLICE)

// geometry: thread = 2 output rows (r0, r0+1) x 1 col; wave = 64 cols, 60 outputs
#define OUTW 60                          // outputs per wave (lanes 2..61)
#define WGCOLS 240                       // 4 waves
#define SEGS 6                           // 1440/240
#define NROWP 361                        // ceil(721/2) row-pairs
#define NWGX (NROWP * SEGS)              // 2166

// ---- ws float layout ----
#define NBANK      128
#define BANKSTRIDE 64
#define WS_ACC     0                     // [NBANK*BANKSTRIDE]
#define ACC_SUM    0        // [26] per (b,l) sums
#define ACC_SSQ    26       // [2]  per-batch total sum-of-squares
#define ACC_GRAD   28
#define ACC_MASS   29
#define N_ACC      30
#define WS_INVDX   (NBANK * BANKSTRIDE)          // [721]
#define WS_FCOR    (WS_INVDX + LATN)             // [721]
#define WS_W       (WS_FCOR + LATN)              // [13]
#define WS_INVDP   (WS_W + NLEV)
#define WS_INV2DP  (WS_INVDP + 1)

constexpr float INV_R     = (float)(1.0 / 6371000.0);
constexpr float INV_DLAT  = (float)(720.0 / M_PI);
constexpr float INV_2DLAT = (float)(360.0 / M_PI);
constexpr float INV_DLON  = (float)(1440.0 / (2.0 * M_PI));
constexpr float INV_2DLON = (float)(720.0 / (2.0 * M_PI));
constexpr float QG_COEF   = 1e-4f;   // F0^2 / N^2

// ---------------- setup: row tables, weights, zero accumulators ----------------
__global__ void pl_setup_kernel(const float* __restrict__ plev, float* __restrict__ ws) {
    const int t = threadIdx.x;
    if (t < LATN) {
        double lat;
        if (t == 0)            lat = (double)(-(float)(M_PI / 2.0));
        else if (t == LATN-1)  lat = (double)( (float)(M_PI / 2.0));
        else                   lat = (double)((float)(-M_PI / 2.0 + (double)t * (M_PI / 720.0)));
        double c = cos(lat);
        if (c < 1e-8) c = 1e-8;                      // matches jnp.clip(cos, 1e-8)
        ws[WS_INVDX + t] = (float)(1.0 / (6371000.0 * c));
        ws[WS_FCOR  + t] = (float)(2.0 * 7.292e-05 * sin(lat));
    }
    if (t < NLEV) {
        float p[NLEV];
        #pragma unroll
        for (int l = 0; l < NLEV; ++l) p[l] = plev[l] * 100.0f;
        float dpl[NLEV-1];
        #pragma unroll
        for (int l = 0; l < NLEV-1; ++l) dpl[l] = p[l+1] - p[l];
        float raw;
        if (t == 0)            raw = dpl[0] * 0.5f;
        else if (t == NLEV-1)  raw = dpl[NLEV-2] * 0.5f;
        else                   raw = (dpl[t-1] + dpl[t]) * 0.5f;
        float s = dpl[0] * 0.5f + dpl[NLEV-2] * 0.5f;
        #pragma unroll
        for (int l = 1; l < NLEV-1; ++l) s += (dpl[l-1] + dpl[l]) * 0.5f;
        if (s < 1e-8f) s = 1e-8f;
        ws[WS_W + t] = raw / s;
    }
    if (t == 0) {
        float sd = 0.f;
        for (int l = 0; l < NLEV-1; ++l) sd += plev[l+1] - plev[l];
        float dp = sd / (float)(NLEV-1) * 100.0f;    // mean(diff)*100 (hPa->Pa)
        ws[WS_INVDP]  = 1.0f / dp;
        ws[WS_INV2DP] = 1.0f / (2.0f * dp);
    }
    for (int z = t; z < NBANK * BANKSTRIDE; z += 1024) ws[WS_ACC + z] = 0.0f;
}

// ---------------- helpers ----------------
__device__ __forceinline__ int swz_nwg(int orig, int nwg) {
    // bijective XCD-chunk swizzle (m204)
    const int q = nwg >> 3, r = nwg & 7;
    const int x = orig & 7, k = orig >> 3;
    return (x < r ? x * (q + 1) : r * (q + 1) + (x - r) * q) + k;
}

// ---------------- fused kernel: 2 output rows/thread, pure-shfl cols, rolling scalars ----------------
__launch_bounds__(256)
__global__ void pl_row2m_kernel(const float* __restrict__ u, const float* __restrict__ v,
                                float* __restrict__ ws)
{
    __shared__ float red[16][17];

    const int tid  = threadIdx.x;
    const int lane = tid & 63, w = tid >> 6;
    const int b  = blockIdx.y;
    const int wg = swz_nwg(blockIdx.x, NWGX);
    const int wgr = wg / SEGS, seg = wg - wgr * SEGS;
    const int r0  = 2 * wgr;                         // 0,2,...,720

    const int out0 = seg * WGCOLS + w * OUTW;
    const int c_un = out0 - 2 + lane;                // lanes 2..61 are outputs
    const int c = max(0, min(c_un, LONN - 1));
    const float ma = (lane >= 2 && lane <= 61) ? 1.f : 0.f;
    const float mb = (r0 + 1 < LATN) ? ma : 0.f;     // row b = 721 only at r0=720
    const bool e0 = (c == 0), e1 = (c == LONN - 1);
    const bool rTop = (r0 == 0), rBotA = (r0 == LATN - 1);

    // clamped row indices for table/loads
    const int crm = max(r0 - 1, 0);
    const int crb = min(r0 + 1, LATN - 1);
    const int crp = min(r0 + 2, LATN - 1);
    const int cu0 = max(r0 - 2, 0), cu1 = crm, cu2 = r0;
    const int cu3 = crb, cu4 = crp, cu5 = min(r0 + 3, LATN - 1);

    const float* ub = u + (size_t)b * BATSTRIDE;
    const float* vb = v + (size_t)b * BATSTRIDE;
    const float idp = ws[WS_INVDP], i2dp = ws[WS_INV2DP];

    // scales (eC folds the column one-sided factor; row one-sided via sr_*)
    const float eC = (e0 || e1) ? INV_DLON : INV_2DLON;
    const float sc_m = eC * ws[WS_INVDX + crm];
    const float sc_a = eC * ws[WS_INVDX + r0];
    const float sc_b = eC * ws[WS_INVDX + crb];
    const float sc_p = eC * ws[WS_INVDX + crp];
    const float sr_a = ((rTop || rBotA) ? INV_DLAT : INV_2DLAT) * INV_R;
    const float sr_mb = INV_2DLAT * INV_R;           // rows rm/rb never grid-edge (parity)
    const float sr_p = ((r0 + 2 >= LATN - 1) ? INV_DLAT : INV_2DLAT) * INV_R;
    const float fc_m = ws[WS_FCOR + crm], fc_a = ws[WS_FCOR + r0];
    const float fc_b = ws[WS_FCOR + crb], fc_p = ws[WS_FCOR + crp];

    // element offsets; level advance = uniform SGPR pointer bump
    const int o_u0 = cu0 * LONN + c, o_u1 = cu1 * LONN + c, o_u2 = cu2 * LONN + c;
    const int o_u3 = cu3 * LONN + c, o_u4 = cu4 * LONN + c, o_u5 = cu5 * LONN + c;
    const int o_vm = crm * LONN + c, o_va = r0 * LONN + c;
    const int o_vb = crb * LONN + c, o_vp = crp * LONN + c;

    float vals[16];
    #pragma unroll
    for (int k = 0; k < 16; ++k) vals[k] = 0.f;
    float ssqt = 0.f, grad = 0.f;
    float wu_a = 0.f, wu_b = 0.f, wvm = 0.f, wva = 0.f, wvb = 0.f, wvp = 0.f;

    auto consume = [&](int k, float qm, float qa, float qb, float qp) {
        const float qx = qa * ma, qy = qb * mb;
        vals[k] += qx + qy;
        ssqt += qx * qx + qy * qy;
        const float gla = (qb - qm) * sr_a;          // rTop/rBot folded via vo selects
        const float glb = (qp - qa) * sr_mb;
        const float qaL = __shfl_up(qa, 1), qaR = __shfl_down(qa, 1);
        const float qbL = __shfl_up(qb, 1), qbR = __shfl_down(qb, 1);
        const float gna = ((e1 ? qa : qaR) - (e0 ? qa : qaL)) * sc_a;
        const float gnb = ((e1 ? qb : qbR) - (e0 ? qb : qbL)) * sc_b;
        grad += ma * (gla * gla + gna * gna) + mb * (glb * glb + gnb * gnb);
    };

    // rolling state ONLY (R8 lesson: NO level-indexed arrays -> no scratch)
    float vo2_m, vo1_m, pa_m, pb_m;
    float vo2_a, vo1_a, pa_a, pb_a;
    float vo2_b, vo1_b, pa_b, pb_b;
    float vo2_p, vo1_p, pa_p, pb_p;

    const float* pu = ub;
    const float* pv = vb;
    #pragma unroll
    for (int l = 0; l < NLEV; ++l) {
        const float wl = ws[WS_W + l];               // uniform -> SGPR
        const float u0 = pu[o_u0], u1 = pu[o_u1], u2 = pu[o_u2];
        const float u3 = pu[o_u3], u4 = pu[o_u4], u5 = pu[o_u5];
        const float vm = pv[o_vm], va = pv[o_va], vbv = pv[o_vb], vpp = pv[o_vp];

        const float vmL = __shfl_up(vm, 1),  vmR = __shfl_down(vm, 1);
        const float vaL = __shfl_up(va, 1),  vaR = __shfl_down(va, 1);
        const float vbL = __shfl_up(vbv, 1), vbR = __shfl_down(vbv, 1);
        const float vpL = __shfl_up(vpp, 1), vpR = __shfl_down(vpp, 1);

        float com = (vmR - vmL) * sc_m - (u2 - u0) * sr_mb;
        float coa = (vaR - vaL) * sc_a - (u3 - u1) * sr_a;
        float cob = (vbR - vbL) * sc_b - (u4 - u2) * sr_mb;
        float cop = (vpR - vpL) * sc_p - (u5 - u3) * sr_p;
        if (rTop)  com = coa;                        // clamped halo row == own row
        if (rBotA) { cob = coa; cop = coa; }

        wu_a = fmaf(wl, u2, wu_a);   wu_b = fmaf(wl, u3, wu_b);
        wvm = fmaf(wl, vm, wvm);     wva = fmaf(wl, va, wva);
        wvb = fmaf(wl, vbv, wvb);    wvp = fmaf(wl, vpp, wvp);

        // fused vertical pipeline (qg[l-2] emitted+consumed; 4 scalars live per row)
        if (l == 0) {
            vo1_m = com; vo1_a = coa; vo1_b = cob; vo1_p = cop;
        } else if (l == 1) {
            pb_m = (com - vo1_m) * idp;  pb_a = (coa - vo1_a) * idp;
            pb_b = (cob - vo1_b) * idp;  pb_p = (cop - vo1_p) * idp;
            vo2_m = vo1_m; vo1_m = com;  vo2_a = vo1_a; vo1_a = coa;
            vo2_b = vo1_b; vo1_b = cob;  vo2_p = vo1_p; vo1_p = cop;
        } else {
            const float pn_m = (com - vo2_m) * i2dp;   // vp1[l-1]
            const float pn_a = (coa - vo2_a) * i2dp;
            const float pn_b = (cob - vo2_b) * i2dp;
            const float pn_p = (cop - vo2_p) * i2dp;
            float qm, qa, qb, qp;
            if (l == 2) {
                qm = vo2_m + fc_m + QG_COEF * ((pn_m - pb_m) * idp);
                qa = vo2_a + fc_a + QG_COEF * ((pn_a - pb_a) * idp);
                qb = vo2_b + fc_b + QG_COEF * ((pn_b - pb_b) * idp);
                qp = vo2_p + fc_p + QG_COEF * ((pn_p - pb_p) * idp);
            } else {
                qm = vo2_m + fc_m + QG_COEF * ((pn_m - pa_m) * i2dp);
                qa = vo2_a + fc_a + QG_COEF * ((pn_a - pa_a) * i2dp);
                qb = vo2_b + fc_b + QG_COEF * ((pn_b - pa_b) * i2dp);
                qp = vo2_p + fc_p + QG_COEF * ((pn_p - pa_p) * i2dp);
            }
            consume(l - 2, qm, qa, qb, qp);
            pa_m = pb_m; pb_m = pn_m;  vo2_m = vo1_m; vo1_m = com;
            pa_a = pb_a; pb_a = pn_a;  vo2_a = vo1_a; vo1_a = coa;
            pa_b = pb_b; pb_b = pn_b;  vo2_b = vo1_b; vo1_b = cob;
            pa_p = pb_p; pb_p = pn_p;  vo2_p = vo1_p; vo1_p = cop;
        }
        pu += SLICE; pv += SLICE;                    // uniform SALU bump
    }
    // tail: vp1[12] one-sided; emit qg[11], qg[12]
    {
        const float p12m = (vo1_m - vo2_m) * idp;
        const float p12a = (vo1_a - vo2_a) * idp;
        const float p12b = (vo1_b - vo2_b) * idp;
        const float p12p = (vo1_p - vo2_p) * idp;
        consume(11, vo2_m + fc_m + QG_COEF * ((p12m - pa_m) * i2dp),
                    vo2_a + fc_a + QG_COEF * ((p12a - pa_a) * i2dp),
                    vo2_b + fc_b + QG_COEF * ((p12b - pa_b) * i2dp),
                    vo2_p + fc_p + QG_COEF * ((p12p - pa_p) * i2dp));
        consume(12, vo1_m + fc_m + QG_COEF * ((p12m - pb_m) * idp),
                    vo1_a + fc_a + QG_COEF * ((p12a - pb_a) * idp),
                    vo1_b + fc_b + QG_COEF * ((p12b - pb_b) * idp),
                    vo1_p + fc_p + QG_COEF * ((p12p - pb_p) * idp));
    }

    vals[13] += ssqt;
    vals[14] += grad;
    // mass: du/dx via wu shfl (+edge selects); dv/dy in-thread (clamped loads -> exact edges)
    {
        const float waL = __shfl_up(wu_a, 1), waR = __shfl_down(wu_a, 1);
        const float wbL = __shfl_up(wu_b, 1), wbR = __shfl_down(wu_b, 1);
        const float cda = ((e1 ? wu_a : waR) - (e0 ? wu_a : waL)) * sc_a + (wvb - wvm) * sr_a;
        const float cdb = ((e1 ? wu_b : wbR) - (e0 ? wu_b : wbL)) * sc_b + (wvp - wva) * sr_mb;
        vals[15] += ma * cda * cda + mb * cdb * cdb;
    }

    // ---- reduction: 4-step 16-lane-group butterfly + LDS transpose (16 values) ----
    #pragma unroll
    for (int k = 0; k < 16; ++k) {
        float x = vals[k];
        x += __shfl_xor(x, 8, 64);
        x += __shfl_xor(x, 4, 64);
        x += __shfl_xor(x, 2, 64);
        x += __shfl_xor(x, 1, 64);
        vals[k] = x;
    }
    const int g = tid >> 4, k16 = tid & 15;
    float myv = vals[0];
    #pragma unroll
    for (int k = 1; k < 16; ++k) if (k16 == k) myv = vals[k];   // static-index select
    red[g][k16] = myv;
    __syncthreads();

    if (tid < 16) {
        const int k = tid;
        float s = 0.f;
        #pragma unroll
        for (int g2 = 0; g2 < 16; ++g2) s += red[g2][k];
        int target;
        if (k < 13)       target = ACC_SUM + b * 13 + k;
        else if (k == 13) target = ACC_SSQ + b;
        else if (k == 14) target = ACC_GRAD;
        else              target = ACC_MASS;
        const int bank = (b * NWGX + blockIdx.x) & (NBANK - 1);
        atomicAdd(&ws[WS_ACC + bank * BANKSTRIDE + target], s);
    }
}

// ---------------- finalize: sum banks, apply formulas ----------------
__global__ void pl_finalize_kernel(const float* __restrict__ ws, float* __restrict__ out) {
    __shared__ float tot[N_ACC];
    const int t = threadIdx.x;
    if (t < N_ACC) {
        float s = 0.f;
        for (int bk = 0; bk < NBANK; ++bk) s += ws[WS_ACC + bk * BANKSTRIDE + t];
        tot[t] = s;
    }
    __syncthreads();
    if (t == 0) {
        const float N = (float)SLICE;
        float s2 = 0.f;
        for (int s = 0; s < 2 * NLEV; ++s) s2 += tot[ACC_SUM + s] * tot[ACC_SUM + s];
        const float ssq = tot[ACC_SSQ + 0] + tot[ACC_SSQ + 1];
        float vmean = (ssq - s2 / N) / (N - 1.0f) * (1.0f / (2.0f * NLEV));
        float gmean = tot[ACC_GRAD] / (float)(NBATCH * NLEV * SLICE);
        float mmean = tot[ACC_MASS] / (float)(NBATCH * SLICE);
        out[0] = vmean + 0.1f * gmean + mmean;          // spectra_loss statically 0
    }
}

extern "C" void kernel_launch(void* const* d_in, const int* in_sizes, int n_in,
                              void* d_out, int out_size, void* d_ws, size_t ws_size,
                              hipStream_t stream) {
    const float* u    = (const float*)d_in[0];
    const float* v    = (const float*)d_in[1];
    const float* plev = (const float*)d_in[2];
    float* ws  = (float*)d_ws;
    float* out = (float*)d_out;

    hipLaunchKernelGGL(pl_setup_kernel, dim3(1), dim3(1024), 0, stream, plev, ws);
    hipLaunchKernelGGL(pl_row2m_kernel, dim3(NWGX, NBATCH), dim3(256), 0, stream, u, v, ws);
    hipLaunchKernelGGL(pl_finalize_kernel, dim3(1), dim3(64), 0, stream, ws, out);
}

// Round 10
// 56.926 us; speedup vs baseline: 3.9576x; 1.1932x over previous
//
#include <hip/hip_runtime.h>
#include <math.h>

#define LATN 721
#define LONN 1440
#define NLEV 13
#define NBATCH 2
#define SLICE (LATN * LONN)              // 1,038,240
#define BATSTRIDE (NLEV * SLICE)

// geometry: thread = 2 output rows x 2 cols (float2); wave = 128 cols, 124 outputs
#define OUTW 124                         // outputs per wave (lanes 1..62, 2 cols each)
#define WGCOLS 496                       // 4 waves
#define SEGS 3                           // ceil(1440/496)
#define NROWP 361                        // ceil(721/2) row-pairs
#define NWGX (NROWP * SEGS)              // 1083

// ---- ws float layout ----
#define NBANK      128
#define BANKSTRIDE 64
#define WS_ACC     0                     // [NBANK*BANKSTRIDE]
#define ACC_SUM    0        // [26] per (b,l) sums
#define ACC_SSQ    26       // [2]  per-batch total sum-of-squares
#define ACC_GRAD   28
#define ACC_MASS   29
#define N_ACC      30
#define WS_INVDX   (NBANK * BANKSTRIDE)          // [721]
#define WS_FCOR    (WS_INVDX + LATN)             // [721]
#define WS_W       (WS_FCOR + LATN)              // [13]
#define WS_INVDP   (WS_W + NLEV)
#define WS_INV2DP  (WS_INVDP + 1)

constexpr float INV_R     = (float)(1.0 / 6371000.0);
constexpr float INV_DLAT  = (float)(720.0 / M_PI);
constexpr float INV_2DLAT = (float)(360.0 / M_PI);
constexpr float INV_DLON  = (float)(1440.0 / (2.0 * M_PI));
constexpr float INV_2DLON = (float)(720.0 / (2.0 * M_PI));
constexpr float QG_COEF   = 1e-4f;   // F0^2 / N^2

// ---------------- setup: row tables, weights, zero accumulators ----------------
__global__ void pl_setup_kernel(const float* __restrict__ plev, float* __restrict__ ws) {
    const int t = threadIdx.x;
    if (t < LATN) {
        double lat;
        if (t == 0)            lat = (double)(-(float)(M_PI / 2.0));
        else if (t == LATN-1)  lat = (double)( (float)(M_PI / 2.0));
        else                   lat = (double)((float)(-M_PI / 2.0 + (double)t * (M_PI / 720.0)));
        double c = cos(lat);
        if (c < 1e-8) c = 1e-8;                      // matches jnp.clip(cos, 1e-8)
        ws[WS_INVDX + t] = (float)(1.0 / (6371000.0 * c));
        ws[WS_FCOR  + t] = (float)(2.0 * 7.292e-05 * sin(lat));
    }
    if (t < NLEV) {
        float p[NLEV];
        #pragma unroll
        for (int l = 0; l < NLEV; ++l) p[l] = plev[l] * 100.0f;
        float dpl[NLEV-1];
        #pragma unroll
        for (int l = 0; l < NLEV-1; ++l) dpl[l] = p[l+1] - p[l];
        float raw;
        if (t == 0)            raw = dpl[0] * 0.5f;
        else if (t == NLEV-1)  raw = dpl[NLEV-2] * 0.5f;
        else                   raw = (dpl[t-1] + dpl[t]) * 0.5f;
        float s = dpl[0] * 0.5f + dpl[NLEV-2] * 0.5f;
        #pragma unroll
        for (int l = 1; l < NLEV-1; ++l) s += (dpl[l-1] + dpl[l]) * 0.5f;
        if (s < 1e-8f) s = 1e-8f;
        ws[WS_W + t] = raw / s;
    }
    if (t == 0) {
        float sd = 0.f;
        for (int l = 0; l < NLEV-1; ++l) sd += plev[l+1] - plev[l];
        float dp = sd / (float)(NLEV-1) * 100.0f;    // mean(diff)*100 (hPa->Pa)
        ws[WS_INVDP]  = 1.0f / dp;
        ws[WS_INV2DP] = 1.0f / (2.0f * dp);
    }
    for (int z = t; z < NBANK * BANKSTRIDE; z += 1024) ws[WS_ACC + z] = 0.0f;
}

// ---------------- helpers ----------------
__device__ __forceinline__ int swz_nwg(int orig, int nwg) {
    // bijective XCD-chunk swizzle (m204)
    const int q = nwg >> 3, r = nwg & 7;
    const int x = orig & 7, k = orig >> 3;
    return (x < r ? x * (q + 1) : r * (q + 1) + (x - r) * q) + k;
}
__device__ __forceinline__ float2 ld2(const float* p) {
    return *reinterpret_cast<const float2*>(p);
}
__device__ __forceinline__ float2 sm2(float2 a, float2 b, float s) {   // (a-b)*s
    return make_float2((a.x - b.x) * s, (a.y - b.y) * s);
}

// ---------------- fused kernel: 2 rows x 2 cols per thread, rolling float2 scalars ----------------
__launch_bounds__(256)
__global__ void pl_rc22_kernel(const float* __restrict__ u, const float* __restrict__ v,
                               float* __restrict__ ws)
{
    __shared__ float red[16][17];

    const int tid  = threadIdx.x;
    const int lane = tid & 63, w = tid >> 6;
    const int b  = blockIdx.y;
    const int wg = swz_nwg(blockIdx.x, NWGX);
    const int wgr = wg / SEGS, seg = wg - wgr * SEGS;
    const int r0  = 2 * wgr;                         // 0,2,...,720

    // columns: lane owns pair (c0, c0+1); lanes 1..62 are outputs, 0/63 shfl halo
    const int out0  = seg * WGCOLS + w * OUTW;
    const int c0_un = out0 - 2 + 2 * lane;           // even
    const int cb = max(0, min(c0_un, LONN - 2));     // 8B-aligned pair base
    const float m0 = (lane >= 1 && lane <= 62 && c0_un     < LONN) ? 1.f : 0.f;
    const float m1 = (lane >= 1 && lane <= 62 && c0_un + 1 < LONN) ? 1.f : 0.f;
    const bool e0 = (c0_un == 0);                    // .x is col 0 (parity: always .x)
    const bool e1 = (c0_un + 1 == LONN - 1);         // .y is col 1439 (always .y)

    // rows: outputs r0 (a), r0+1 (b); vort rows m=r0-1, a, b, p=r0+2
    const bool rTop = (r0 == 0), rBotA = (r0 == LATN - 1);
    const float rbf = (r0 + 1 < LATN) ? 1.f : 0.f;
    const float mb0 = m0 * rbf, mb1 = m1 * rbf;
    const int crm = max(r0 - 1, 0);
    const int crb = min(r0 + 1, LATN - 1);
    const int crp = min(r0 + 2, LATN - 1);
    const int cu0 = max(r0 - 2, 0), cu1 = crm, cu2 = r0;
    const int cu3 = crb, cu4 = crp, cu5 = min(r0 + 3, LATN - 1);

    const float* ub = u + (size_t)b * BATSTRIDE;
    const float* vb = v + (size_t)b * BATSTRIDE;
    const float idp = ws[WS_INVDP], i2dp = ws[WS_INV2DP];

    // scales: eC0/eC1 fold per-column one-sided factor
    const float eC0 = e0 ? INV_DLON : INV_2DLON;
    const float eC1 = e1 ? INV_DLON : INV_2DLON;
    const float ixm = ws[WS_INVDX + crm], ixa = ws[WS_INVDX + r0];
    const float ixb = ws[WS_INVDX + crb], ixp = ws[WS_INVDX + crp];
    const float sm0 = eC0 * ixm, sm1 = eC1 * ixm;
    const float sa0 = eC0 * ixa, sa1 = eC1 * ixa;
    const float sb0 = eC0 * ixb, sb1 = eC1 * ixb;
    const float sp0 = eC0 * ixp, sp1 = eC1 * ixp;
    const float sr_a = ((rTop || rBotA) ? INV_DLAT : INV_2DLAT) * INV_R;
    const float sr_mb = INV_2DLAT * INV_R;           // rows m/b never grid-edge (parity)
    const float sr_p = ((r0 + 2 >= LATN - 1) ? INV_DLAT : INV_2DLAT) * INV_R;
    const float fc_m = ws[WS_FCOR + crm], fc_a = ws[WS_FCOR + r0];
    const float fc_b = ws[WS_FCOR + crb], fc_p = ws[WS_FCOR + crp];

    // element offsets (pair base); level advance = uniform SGPR pointer bump
    const int o_u0 = cu0 * LONN + cb, o_u1 = cu1 * LONN + cb, o_u2 = cu2 * LONN + cb;
    const int o_u3 = cu3 * LONN + cb, o_u4 = cu4 * LONN + cb, o_u5 = cu5 * LONN + cb;
    const int o_vm = crm * LONN + cb, o_va = r0 * LONN + cb;
    const int o_vb = crb * LONN + cb, o_vp = crp * LONN + cb;

    float vals[16];
    #pragma unroll
    for (int k = 0; k < 16; ++k) vals[k] = 0.f;
    float ssqt = 0.f, grad = 0.f;
    float2 wu_a = make_float2(0.f, 0.f), wu_b = make_float2(0.f, 0.f);
    float2 wvm = make_float2(0.f, 0.f), wva = make_float2(0.f, 0.f);
    float2 wvb = make_float2(0.f, 0.f), wvp = make_float2(0.f, 0.f);

    auto qgf = [&](float2 vo, float fc, float2 vpp) -> float2 {
        return make_float2(vo.x + fc + QG_COEF * vpp.x, vo.y + fc + QG_COEF * vpp.y);
    };
    auto consume = [&](int k, float2 qm, float2 qa, float2 qb, float2 qp) {
        const float qax = qa.x * m0,  qay = qa.y * m1;
        const float qbx = qb.x * mb0, qby = qb.y * mb1;
        vals[k] += (qax + qay) + (qbx + qby);
        ssqt += qax * qax + qay * qay + qbx * qbx + qby * qby;
        const float2 gla = sm2(qb, qm, sr_a);        // row clamps folded via vo selects
        const float2 glb = sm2(qp, qa, sr_mb);
        const float qaL = __shfl_up(qa.y, 1), qaR = __shfl_down(qa.x, 1);
        const float qbL = __shfl_up(qb.y, 1), qbR = __shfl_down(qb.x, 1);
        const float gnax = (qa.y - (e0 ? qa.x : qaL)) * sa0;
        const float gnay = ((e1 ? qa.y : qaR) - qa.x) * sa1;
        const float gnbx = (qb.y - (e0 ? qb.x : qbL)) * sb0;
        const float gnby = ((e1 ? qb.y : qbR) - qb.x) * sb1;
        grad += m0  * (gla.x * gla.x + gnax * gnax) + m1  * (gla.y * gla.y + gnay * gnay)
              + mb0 * (glb.x * glb.x + gnbx * gnbx) + mb1 * (glb.y * glb.y + gnby * gnby);
    };

    // rolling state ONLY (R8 lesson: NO level-indexed arrays -> no scratch)
    float2 vo2_m, vo1_m, pa_m, pb_m;
    float2 vo2_a, vo1_a, pa_a, pb_a;
    float2 vo2_b, vo1_b, pa_b, pb_b;
    float2 vo2_p, vo1_p, pa_p, pb_p;

    const float* pu = ub;
    const float* pv = vb;
    #pragma unroll
    for (int l = 0; l < NLEV; ++l) {
        const float wl = ws[WS_W + l];               // uniform -> SGPR
        const float2 u0 = ld2(pu + o_u0), u1 = ld2(pu + o_u1), u2 = ld2(pu + o_u2);
        const float2 u3 = ld2(pu + o_u3), u4 = ld2(pu + o_u4), u5 = ld2(pu + o_u5);
        const float2 vm = ld2(pv + o_vm), va = ld2(pv + o_va);
        const float2 vbv = ld2(pv + o_vb), vpv = ld2(pv + o_vp);

        // col neighbors: interior in-lane (.x/.y), boundary via 1-step shfl, grid-edge select
        const float vmL = __shfl_up(vm.y, 1),  vmR = __shfl_down(vm.x, 1);
        const float vaL = __shfl_up(va.y, 1),  vaR = __shfl_down(va.x, 1);
        const float vbL = __shfl_up(vbv.y, 1), vbR = __shfl_down(vbv.x, 1);
        const float vpL = __shfl_up(vpv.y, 1), vpR = __shfl_down(vpv.x, 1);

        float2 com, coa, cob, cop;
        com.x = (vm.y - (e0 ? vm.x : vmL)) * sm0 - (u2.x - u0.x) * sr_mb;
        com.y = ((e1 ? vm.y : vmR) - vm.x) * sm1 - (u2.y - u0.y) * sr_mb;
        coa.x = (va.y - (e0 ? va.x : vaL)) * sa0 - (u3.x - u1.x) * sr_a;
        coa.y = ((e1 ? va.y : vaR) - va.x) * sa1 - (u3.y - u1.y) * sr_a;
        cob.x = (vbv.y - (e0 ? vbv.x : vbL)) * sb0 - (u4.x - u2.x) * sr_mb;
        cob.y = ((e1 ? vbv.y : vbR) - vbv.x) * sb1 - (u4.y - u2.y) * sr_mb;
        cop.x = (vpv.y - (e0 ? vpv.x : vpL)) * sp0 - (u5.x - u3.x) * sr_p;
        cop.y = ((e1 ? vpv.y : vpR) - vpv.x) * sp1 - (u5.y - u3.y) * sr_p;
        if (rTop)  com = coa;                        // clamped halo row == own row
        if (rBotA) { cob = coa; cop = coa; }

        wu_a.x = fmaf(wl, u2.x, wu_a.x);  wu_a.y = fmaf(wl, u2.y, wu_a.y);
        wu_b.x = fmaf(wl, u3.x, wu_b.x);  wu_b.y = fmaf(wl, u3.y, wu_b.y);
        wvm.x = fmaf(wl, vm.x, wvm.x);    wvm.y = fmaf(wl, vm.y, wvm.y);
        wva.x = fmaf(wl, va.x, wva.x);    wva.y = fmaf(wl, va.y, wva.y);
        wvb.x = fmaf(wl, vbv.x, wvb.x);   wvb.y = fmaf(wl, vbv.y, wvb.y);
        wvp.x = fmaf(wl, vpv.x, wvp.x);   wvp.y = fmaf(wl, vpv.y, wvp.y);

        // fused vertical pipeline: qg[l-2] emitted+consumed inside the loop
        if (l == 0) {
            vo1_m = com; vo1_a = coa; vo1_b = cob; vo1_p = cop;
        } else if (l == 1) {
            pb_m = sm2(com, vo1_m, idp);  pb_a = sm2(coa, vo1_a, idp);
            pb_b = sm2(cob, vo1_b, idp);  pb_p = sm2(cop, vo1_p, idp);
            vo2_m = vo1_m; vo1_m = com;   vo2_a = vo1_a; vo1_a = coa;
            vo2_b = vo1_b; vo1_b = cob;   vo2_p = vo1_p; vo1_p = cop;
        } else {
            const float2 pn_m = sm2(com, vo2_m, i2dp);   // vp1[l-1]
            const float2 pn_a = sm2(coa, vo2_a, i2dp);
            const float2 pn_b = sm2(cob, vo2_b, i2dp);
            const float2 pn_p = sm2(cop, vo2_p, i2dp);
            float2 qm, qa, qb, qp;
            if (l == 2) {
                qm = qgf(vo2_m, fc_m, sm2(pn_m, pb_m, idp));
                qa = qgf(vo2_a, fc_a, sm2(pn_a, pb_a, idp));
                qb = qgf(vo2_b, fc_b, sm2(pn_b, pb_b, idp));
                qp = qgf(vo2_p, fc_p, sm2(pn_p, pb_p, idp));
            } else {
                qm = qgf(vo2_m, fc_m, sm2(pn_m, pa_m, i2dp));
                qa = qgf(vo2_a, fc_a, sm2(pn_a, pa_a, i2dp));
                qb = qgf(vo2_b, fc_b, sm2(pn_b, pa_b, i2dp));
                qp = qgf(vo2_p, fc_p, sm2(pn_p, pa_p, i2dp));
            }
            consume(l - 2, qm, qa, qb, qp);
            pa_m = pb_m; pb_m = pn_m;  vo2_m = vo1_m; vo1_m = com;
            pa_a = pb_a; pb_a = pn_a;  vo2_a = vo1_a; vo1_a = coa;
            pa_b = pb_b; pb_b = pn_b;  vo2_b = vo1_b; vo1_b = cob;
            pa_p = pb_p; pb_p = pn_p;  vo2_p = vo1_p; vo1_p = cop;
        }
        pu += SLICE; pv += SLICE;                    // uniform SALU bump
    }
    // tail: vp1[12] one-sided; emit qg[11], qg[12]
    {
        const float2 p12m = sm2(vo1_m, vo2_m, idp);
        const float2 p12a = sm2(vo1_a, vo2_a, idp);
        const float2 p12b = sm2(vo1_b, vo2_b, idp);
        const float2 p12p = sm2(vo1_p, vo2_p, idp);
        consume(11, qgf(vo2_m, fc_m, sm2(p12m, pa_m, i2dp)),
                    qgf(vo2_a, fc_a, sm2(p12a, pa_a, i2dp)),
                    qgf(vo2_b, fc_b, sm2(p12b, pa_b, i2dp)),
                    qgf(vo2_p, fc_p, sm2(p12p, pa_p, i2dp)));
        consume(12, qgf(vo1_m, fc_m, sm2(p12m, pb_m, idp)),
                    qgf(vo1_a, fc_a, sm2(p12a, pb_a, idp)),
                    qgf(vo1_b, fc_b, sm2(p12b, pb_b, idp)),
                    qgf(vo1_p, fc_p, sm2(p12p, pb_p, idp)));
    }

    vals[13] += ssqt;
    vals[14] += grad;
    // mass: du/dx in-lane/shfl + edge selects; dv/dy in-thread (clamped loads -> exact edges)
    {
        const float waL = __shfl_up(wu_a.y, 1), waR = __shfl_down(wu_a.x, 1);
        const float wbL = __shfl_up(wu_b.y, 1), wbR = __shfl_down(wu_b.x, 1);
        const float cdax = (wu_a.y - (e0 ? wu_a.x : waL)) * sa0 + (wvb.x - wvm.x) * sr_a;
        const float cday = ((e1 ? wu_a.y : waR) - wu_a.x) * sa1 + (wvb.y - wvm.y) * sr_a;
        const float cdbx = (wu_b.y - (e0 ? wu_b.x : wbL)) * sb0 + (wvp.x - wva.x) * sr_mb;
        const float cdby = ((e1 ? wu_b.y : wbR) - wu_b.x) * sb1 + (wvp.y - wva.y) * sr_mb;
        vals[15] += m0 * cdax * cdax + m1 * cday * cday
                  + mb0 * cdbx * cdbx + mb1 * cdby * cdby;
    }

    // ---- reduction: 4-step 16-lane-group butterfly + LDS transpose (16 values) ----
    #pragma unroll
    for (int k = 0; k < 16; ++k) {
        float x = vals[k];
        x += __shfl_xor(x, 8, 64);
        x += __shfl_xor(x, 4, 64);
        x += __shfl_xor(x, 2, 64);
        x += __shfl_xor(x, 1, 64);
        vals[k] = x;
    }
    const int g = tid >> 4, k16 = tid & 15;
    float myv = vals[0];
    #pragma unroll
    for (int k = 1; k < 16; ++k) if (k16 == k) myv = vals[k];   // static-index select
    red[g][k16] = myv;
    __syncthreads();

    if (tid < 16) {
        const int k = tid;
        float s = 0.f;
        #pragma unroll
        for (int g2 = 0; g2 < 16; ++g2) s += red[g2][k];
        int target;
        if (k < 13)       target = ACC_SUM + b * 13 + k;
        else if (k == 13) target = ACC_SSQ + b;
        else if (k == 14) target = ACC_GRAD;
        else              target = ACC_MASS;
        const int bank = (b * NWGX + blockIdx.x) & (NBANK - 1);
        atomicAdd(&ws[WS_ACC + bank * BANKSTRIDE + target], s);
    }
}

// ---------------- finalize: sum banks, apply formulas ----------------
__global__ void pl_finalize_kernel(const float* __restrict__ ws, float* __restrict__ out) {
    __shared__ float tot[N_ACC];
    const int t = threadIdx.x;
    if (t < N_ACC) {
        float s = 0.f;
        for (int bk = 0; bk < NBANK; ++bk) s += ws[WS_ACC + bk * BANKSTRIDE + t];
        tot[t] = s;
    }
    __syncthreads();
    if (t == 0) {
        const float N = (float)SLICE;
        float s2 = 0.f;
        for (int s = 0; s < 2 * NLEV; ++s) s2 += tot[ACC_SUM + s] * tot[ACC_SUM + s];
        const float ssq = tot[ACC_SSQ + 0] + tot[ACC_SSQ + 1];
        float vmean = (ssq - s2 / N) / (N - 1.0f) * (1.0f / (2.0f * NLEV));
        float gmean = tot[ACC_GRAD] / (float)(NBATCH * NLEV * SLICE);
        float mmean = tot[ACC_MASS] / (float)(NBATCH * SLICE);
        out[0] = vmean + 0.1f * gmean + mmean;          // spectra_loss statically 0
    }
}

extern "C" void kernel_launch(void* const* d_in, const int* in_sizes, int n_in,
                              void* d_out, int out_size, void* d_ws, size_t ws_size,
                              hipStream_t stream) {
    const float* u    = (const float*)d_in[0];
    const float* v    = (const float*)d_in[1];
    const float* plev = (const float*)d_in[2];
    float* ws  = (float*)d_ws;
    float* out = (float*)d_out;

    hipLaunchKernelGGL(pl_setup_kernel, dim3(1), dim3(1024), 0, stream, plev, ws);
    hipLaunchKernelGGL(pl_rc22_kernel, dim3(NWGX, NBATCH), dim3(256), 0, stream, u, v, ws);
    hipLaunchKernelGGL(pl_finalize_kernel, dim3(1), dim3(64), 0, stream, ws, out);
}